// Round 2
// baseline (13346.800 us; speedup 1.0000x reference)
//
#include <hip/hip_runtime.h>

#define B_ 64
#define S_ 256
#define H_ 1024

typedef float f32x4 __attribute__((ext_vector_type(4)));
typedef _Float16 f16x8 __attribute__((ext_vector_type(8)));

__device__ __forceinline__ unsigned short f2h_u(float f){
  union { _Float16 h; unsigned short u; } cv;
  cv.h = (_Float16)f;
  return cv.u;
}
__device__ __forceinline__ float sigmoidf_(float x){
  return 1.0f / (1.0f + __expf(-x));
}

// ---------- conversion: x (B,S,I) f32 -> (S,B,I) f16 ----------
__global__ __launch_bounds__(256) void cvt_x(const float* __restrict__ in,
                                             unsigned short* __restrict__ out){
  int idx = blockIdx.x * 256 + threadIdx.x;     // 4,194,304 threads, 4 elems each
  int d4 = idx * 4;
  int s = d4 >> 16, b = (d4 >> 10) & 63, k = d4 & 1023;
  const float4 v = *(const float4*)(in + (size_t)b * 262144 + (size_t)s * 1024 + k);
  ushort4 o;
  o.x = f2h_u(v.x); o.y = f2h_u(v.y); o.z = f2h_u(v.z); o.w = f2h_u(v.w);
  *(ushort4*)(out + d4) = o;
}

// ---------- pack 8 (H,H) f32 matrices into [8192][1024] f16 ----------
// row j = bi*32 + cl*8 + m  <-  mats[m][bi*4 + cl][:]   (bi = 0..255, cl = 0..3)
struct P8 { const float* p[8]; };

__global__ __launch_bounds__(256) void pack8(P8 mats, unsigned short* __restrict__ out){
  int idx = blockIdx.x * 256 + threadIdx.x;     // 2,097,152 threads
  int d4 = idx * 4;
  int j = d4 >> 10, k = d4 & 1023;
  int m = j & 7, cl = (j >> 3) & 3, bi = j >> 5;
  const float4 v = *(const float4*)(mats.p[m] + (size_t)(bi * 4 + cl) * 1024 + k);
  ushort4 o;
  o.x = f2h_u(v.x); o.y = f2h_u(v.y); o.z = f2h_u(v.z); o.w = f2h_u(v.w);
  *(ushort4*)(out + d4) = o;
}

// ---------- persistent recurrence ----------
// 256 blocks x 256 threads (cooperative). Block bi owns output columns
// n0 = bi*4 (4 cols x 8 matrices = 32 packed weight rows). U- and W-slices
// live in registers. Per step: MFMA (swapped operands: A=weights, B=h / x),
// cross-wave K-reduction in LDS, per-thread gate combine with c in regs,
// h ping-pong in f16 through global, grid barrier.

__global__ __launch_bounds__(256, 1) void lstm_rec(
    const unsigned short* __restrict__ Xh,   // (S,B,I) f16
    const unsigned short* __restrict__ Up,   // packed [8192][1024] f16
    const unsigned short* __restrict__ Wp,   // packed [8192][1024] f16
    const float* __restrict__ bF, const float* __restrict__ bI,
    const float* __restrict__ bO, const float* __restrict__ bC,
    unsigned short* __restrict__ hbuf,       // [2][65536] f16 ping-pong
    float* __restrict__ out,                 // (B,S,H) f32 + h(65536) + c(65536)
    unsigned int* __restrict__ ctr){
  const int tid = threadIdx.x, wave = tid >> 6, lane = tid & 63;
  const int bi = blockIdx.x, n0 = bi * 4, j0 = bi * 32;
  const int r = lane & 15, q = lane >> 4;
  __shared__ __align__(16) float part[4][64][68];

  // preload weight fragments: wave covers K slice [wave*256, wave*256+256)
  f16x8 uf[2][8], wf[2][8];
#pragma unroll
  for (int nt = 0; nt < 2; ++nt)
#pragma unroll
    for (int kk = 0; kk < 8; ++kk){
      size_t off = (size_t)(j0 + nt * 16 + r) * 1024 + wave * 256 + kk * 32 + q * 8;
      uf[nt][kk] = *(const f16x8*)(Up + off);
      wf[nt][kk] = *(const f16x8*)(Wp + off);
    }

  const int cb = tid >> 2, cl = tid & 3;   // combine: thread owns (batch cb, col cl)
  const float bFv = bF[n0 + cl], bIv = bI[n0 + cl], bOv = bO[n0 + cl], bCv = bC[n0 + cl];
  float c_reg = 0.f;

#pragma unroll 1
  for (int s = 0; s < 256; ++s){
    const unsigned short* hb = hbuf + (size_t)(s & 1) * 65536;
    const unsigned short* xs = Xh + (size_t)s * 65536;
    f32x4 ah[2][4], ax[2][4];
#pragma unroll
    for (int nt = 0; nt < 2; ++nt)
#pragma unroll
      for (int mt = 0; mt < 4; ++mt){ ah[nt][mt] = 0.f; ax[nt][mt] = 0.f; }

#pragma unroll
    for (int kk = 0; kk < 8; ++kk){
      const int k = wave * 256 + kk * 32 + q * 8;
      f16x8 hf[4], xf[4];
#pragma unroll
      for (int mt = 0; mt < 4; ++mt){
        hf[mt] = *(const f16x8*)(hb + (size_t)(mt * 16 + r) * 1024 + k);
        xf[mt] = *(const f16x8*)(xs + (size_t)(mt * 16 + r) * 1024 + k);
      }
#pragma unroll
      for (int nt = 0; nt < 2; ++nt)
#pragma unroll
        for (int mt = 0; mt < 4; ++mt){
          ah[nt][mt] = __builtin_amdgcn_mfma_f32_16x16x32_f16(uf[nt][kk], hf[mt], ah[nt][mt], 0, 0, 0);
          ax[nt][mt] = __builtin_amdgcn_mfma_f32_16x16x32_f16(wf[nt][kk], xf[mt], ax[nt][mt], 0, 0, 0);
        }
    }

    // D[row=nl=nt*16+q*4+rg][col=b=mt*16+r] -> part[wave][b][nl] (h) / [32+nl] (x)
#pragma unroll
    for (int nt = 0; nt < 2; ++nt)
#pragma unroll
      for (int mt = 0; mt < 4; ++mt){
        *(f32x4*)&part[wave][mt * 16 + r][nt * 16 + q * 4]      = ah[nt][mt];
        *(f32x4*)&part[wave][mt * 16 + r][32 + nt * 16 + q * 4] = ax[nt][mt];
      }
    __syncthreads();

    // combine: nl = cl*8 + m, m = 0..7 = [lin_f, mask_f, lin_i, mask_i, lin_o, mask_o, lin_c, mask_c]
    f32x4 y0 = 0.f, y1 = 0.f, z0 = 0.f, z1 = 0.f;
#pragma unroll
    for (int w = 0; w < 4; ++w){
      y0 += *(const f32x4*)&part[w][cb][cl * 8];
      y1 += *(const f32x4*)&part[w][cb][cl * 8 + 4];
      z0 += *(const f32x4*)&part[w][cb][32 + cl * 8];
      z1 += *(const f32x4*)&part[w][cb][32 + cl * 8 + 4];
    }

    size_t grow = ((size_t)cb * 256 + s) * 1024 + n0 + cl;
    float fg = sigmoidf_(z0[0] * sigmoidf_(z0[1]) + y0[0] * sigmoidf_(y0[1]) + bFv);
    float ig = sigmoidf_(z0[2] * sigmoidf_(z0[3]) + y0[2] * sigmoidf_(y0[3]) + bIv);
    float og = sigmoidf_(z1[0] * sigmoidf_(z1[1]) + y1[0] * sigmoidf_(y1[1]) + bOv);
    float cg = tanhf   (z1[2] * sigmoidf_(z1[3]) + y1[2] * sigmoidf_(y1[3]) + bCv);
    c_reg = cg * ig + fg * c_reg;
    float h = og * c_reg;
    out[grow] = h;
    hbuf[(size_t)((s + 1) & 1) * 65536 + (size_t)cb * 1024 + n0 + cl] = f2h_u(h);
    if (s == 255){
      out[16777216 + cb * 1024 + n0 + cl] = h;
      out[16777216 + 65536 + cb * 1024 + n0 + cl] = c_reg;
    }
    if (s == 255) break;   // no barrier needed after last step

    // ---- grid barrier ----
    __threadfence();        // release h writes to agent scope (wbL2)
    __syncthreads();
    if (tid == 0){
      __hip_atomic_fetch_add(ctr, 1u, __ATOMIC_RELAXED, __HIP_MEMORY_SCOPE_AGENT);
      unsigned tgt = (unsigned)(s + 1) * 256u;
      while (__hip_atomic_load(ctr, __ATOMIC_RELAXED, __HIP_MEMORY_SCOPE_AGENT) < tgt)
        __builtin_amdgcn_s_sleep(2);
    }
    __syncthreads();
    __builtin_amdgcn_fence(__ATOMIC_ACQUIRE, "agent");   // invalidate L1/L2 before reading new h
  }
}

// ---------- host launch ----------
extern "C" void kernel_launch(void* const* d_in, const int* in_sizes, int n_in,
                              void* d_out, int out_size, void* d_ws, size_t ws_size,
                              hipStream_t stream){
  (void)in_sizes; (void)n_in; (void)out_size; (void)ws_size;
  char* ws = (char*)d_ws;
  unsigned short* xh   = (unsigned short*)(ws);               // 33,554,432 B
  unsigned short* up   = (unsigned short*)(ws + 33554432);    // 16,777,216 B
  unsigned short* wp   = (unsigned short*)(ws + 50331648);    // 16,777,216 B
  unsigned short* hbuf = (unsigned short*)(ws + 67108864);    //    262,144 B
  unsigned int*   ctr  = (unsigned int*)  (ws + 67371008);    //        256 B
  // total: 67,371,264 B (~64.3 MB)

  hipMemsetAsync(hbuf, 0, 262144 + 256, stream);   // h ping-pong zeros + ctr reset

  cvt_x<<<16384, 256, 0, stream>>>((const float*)d_in[0], xh);
  P8 w8, u8;
  for (int m = 0; m < 8; ++m){
    w8.p[m] = (const float*)d_in[1 + m];
    u8.p[m] = (const float*)d_in[9 + m];
  }
  pack8<<<8192, 256, 0, stream>>>(w8, wp);
  pack8<<<8192, 256, 0, stream>>>(u8, up);

  const float* bF = (const float*)d_in[17];
  const float* bI = (const float*)d_in[18];
  const float* bO = (const float*)d_in[19];
  const float* bC = (const float*)d_in[20];
  float* outp = (float*)d_out;

  void* args[] = { (void*)&xh, (void*)&up, (void*)&wp,
                   (void*)&bF, (void*)&bI, (void*)&bO, (void*)&bC,
                   (void*)&hbuf, (void*)&outp, (void*)&ctr };
  hipError_t e = hipLaunchCooperativeKernel((const void*)lstm_rec, dim3(256), dim3(256),
                                            args, 0u, stream);
  if (e != hipSuccess){
    // fallback: plain launch (256 blocks on 256 CUs, 1 block/CU resources)
    lstm_rec<<<256, 256, 0, stream>>>(xh, up, wp, bF, bI, bO, bC, hbuf, outp, ctr);
  }
}

// Round 3
// 2560.065 us; speedup vs baseline: 5.2135x; 5.2135x over previous
//
#include <hip/hip_runtime.h>

#define B_ 64
#define S_ 256
#define H_ 1024

typedef float f32x4 __attribute__((ext_vector_type(4)));
typedef _Float16 f16x8 __attribute__((ext_vector_type(8)));

__device__ __forceinline__ unsigned short f2h_u(float f){
  union { _Float16 h; unsigned short u; } cv; cv.h = (_Float16)f; return cv.u;
}
__device__ __forceinline__ float sigmoidf_(float x){ return 1.0f / (1.0f + __expf(-x)); }

// ---------- conversion: x (B,S,I) f32 -> (S,B,I) f16 ----------
__global__ __launch_bounds__(256) void cvt_x(const float* __restrict__ in,
                                             unsigned short* __restrict__ out){
  int idx = blockIdx.x * 256 + threadIdx.x;
  int d4 = idx * 4;
  int s = d4 >> 16, b = (d4 >> 10) & 63, k = d4 & 1023;
  const float4 v = *(const float4*)(in + (size_t)b * 262144 + (size_t)s * 1024 + k);
  ushort4 o;
  o.x = f2h_u(v.x); o.y = f2h_u(v.y); o.z = f2h_u(v.z); o.w = f2h_u(v.w);
  *(ushort4*)(out + d4) = o;
}

// ---------- pack 8 (H,H) f32 matrices into [8192][1024] f16 ----------
// row j = bi*32 + cl*8 + m  <-  mats[m][bi*4 + cl][:]
struct P8 { const float* p[8]; };

__global__ __launch_bounds__(256) void pack8(P8 mats, unsigned short* __restrict__ out){
  int idx = blockIdx.x * 256 + threadIdx.x;
  int d4 = idx * 4;
  int j = d4 >> 10, k = d4 & 1023;
  int m = j & 7, cl = (j >> 3) & 3, bi = j >> 5;
  const float4 v = *(const float4*)(mats.p[m] + (size_t)(bi * 4 + cl) * 1024 + k);
  ushort4 o;
  o.x = f2h_u(v.x); o.y = f2h_u(v.y); o.z = f2h_u(v.z); o.w = f2h_u(v.w);
  *(ushort4*)(out + d4) = o;
}

// ---------- persistent recurrence ----------
// 256 blocks x 256 threads (cooperative). Block bi owns output columns n0=bi*4.
// h history: hhist[s] read at step s (plain cached loads — each slot is
// write-once/read-once so stale lines cannot exist), hhist[s+1] written
// write-through (sc0 sc1) and drained before the flag store. Flag-array
// barrier: flags[bi]=s+1; wave0 polls all 256 flags with one dwordx4/lane.

__global__ __launch_bounds__(256, 1) void lstm_rec(
    const unsigned short* __restrict__ Xh,   // (S,B,I) f16
    const unsigned short* __restrict__ Up,   // packed [8192][1024] f16
    const unsigned short* __restrict__ Wp,   // packed [8192][1024] f16
    const float* __restrict__ bF, const float* __restrict__ bI,
    const float* __restrict__ bO, const float* __restrict__ bC,
    unsigned short* __restrict__ hhist,      // [257][65536] f16
    unsigned int* __restrict__ flags,        // [256]
    float* __restrict__ out){                // (B,S,H) f32 + h(65536) + c(65536)
  const int tid = threadIdx.x, wave = tid >> 6, lane = tid & 63;
  const int bi = blockIdx.x, n0 = bi * 4, j0 = bi * 32;
  const int r = lane & 15, q = lane >> 4;
  __shared__ __align__(16) float part[4][64][68];

  // preload weight fragments: wave covers K slice [wave*256, wave*256+256)
  f16x8 uf[2][8], wf[2][8];
#pragma unroll
  for (int nt = 0; nt < 2; ++nt)
#pragma unroll
    for (int kk = 0; kk < 8; ++kk){
      size_t off = (size_t)(j0 + nt * 16 + r) * 1024 + wave * 256 + kk * 32 + q * 8;
      uf[nt][kk] = *(const f16x8*)(Up + off);
      wf[nt][kk] = *(const f16x8*)(Wp + off);
    }

  const int cb = tid >> 2, cl = tid & 3;   // combine: thread owns (batch cb, col cl)
  const float bFv = bF[n0 + cl], bIv = bI[n0 + cl], bOv = bO[n0 + cl], bCv = bC[n0 + cl];
  float c_reg = 0.f;

#pragma unroll 1
  for (int s = 0; s < 256; ++s){
    // ---- Phase A: x-side MFMAs (read-only x; hides under arrival skew) ----
    const unsigned short* xs = Xh + (size_t)s * 65536;
    f32x4 ax[2][4];
#pragma unroll
    for (int nt = 0; nt < 2; ++nt)
#pragma unroll
      for (int mt = 0; mt < 4; ++mt) ax[nt][mt] = 0.f;
#pragma unroll
    for (int kk = 0; kk < 8; ++kk){
      const int k = wave * 256 + kk * 32 + q * 8;
      f16x8 xf[4];
#pragma unroll
      for (int mt = 0; mt < 4; ++mt)
        xf[mt] = *(const f16x8*)(xs + (size_t)(mt * 16 + r) * 1024 + k);
#pragma unroll
      for (int nt = 0; nt < 2; ++nt)
#pragma unroll
        for (int mt = 0; mt < 4; ++mt)
          ax[nt][mt] = __builtin_amdgcn_mfma_f32_16x16x32_f16(wf[nt][kk], xf[mt], ax[nt][mt], 0, 0, 0);
    }

    // ---- Phase B: wait for step-s h (all flags >= s) ----
    if (s > 0){
      if (wave == 0){
        const uint4* fl = (const uint4*)flags;
        const unsigned tgt = (unsigned)s;
        for (;;){
          uint4 v;
          asm volatile("global_load_dwordx4 %0, %1, off sc0 sc1\n\t"
                       "s_waitcnt vmcnt(0)"
                       : "=v"(v) : "v"(fl + lane) : "memory");
          int ok = (v.x >= tgt) & (v.y >= tgt) & (v.z >= tgt) & (v.w >= tgt);
          if (__all(ok)) break;
          __builtin_amdgcn_s_sleep(1);
        }
      }
      __syncthreads();
    }

    // ---- Phase C: h-side MFMAs (plain cached loads; slot never stale) ----
    const unsigned short* hb = hhist + (size_t)s * 65536;
    f32x4 ah[2][4];
#pragma unroll
    for (int nt = 0; nt < 2; ++nt)
#pragma unroll
      for (int mt = 0; mt < 4; ++mt) ah[nt][mt] = 0.f;
#pragma unroll
    for (int kk = 0; kk < 8; ++kk){
      const int k = wave * 256 + kk * 32 + q * 8;
      f16x8 hf[4];
#pragma unroll
      for (int mt = 0; mt < 4; ++mt)
        hf[mt] = *(const f16x8*)(hb + (size_t)(mt * 16 + r) * 1024 + k);
#pragma unroll
      for (int nt = 0; nt < 2; ++nt)
#pragma unroll
        for (int mt = 0; mt < 4; ++mt)
          ah[nt][mt] = __builtin_amdgcn_mfma_f32_16x16x32_f16(uf[nt][kk], hf[mt], ah[nt][mt], 0, 0, 0);
    }

    // ---- Phase D: cross-wave reduce + gate combine ----
#pragma unroll
    for (int nt = 0; nt < 2; ++nt)
#pragma unroll
      for (int mt = 0; mt < 4; ++mt){
        *(f32x4*)&part[wave][mt * 16 + r][nt * 16 + q * 4]      = ah[nt][mt];
        *(f32x4*)&part[wave][mt * 16 + r][32 + nt * 16 + q * 4] = ax[nt][mt];
      }
    __syncthreads();

    f32x4 y0 = 0.f, y1 = 0.f, z0 = 0.f, z1 = 0.f;
#pragma unroll
    for (int w = 0; w < 4; ++w){
      y0 += *(const f32x4*)&part[w][cb][cl * 8];
      y1 += *(const f32x4*)&part[w][cb][cl * 8 + 4];
      z0 += *(const f32x4*)&part[w][cb][32 + cl * 8];
      z1 += *(const f32x4*)&part[w][cb][32 + cl * 8 + 4];
    }

    size_t grow = ((size_t)cb * 256 + s) * 1024 + n0 + cl;
    float fg = sigmoidf_(z0[0] * sigmoidf_(z0[1]) + y0[0] * sigmoidf_(y0[1]) + bFv);
    float ig = sigmoidf_(z0[2] * sigmoidf_(z0[3]) + y0[2] * sigmoidf_(y0[3]) + bIv);
    float og = sigmoidf_(z1[0] * sigmoidf_(z1[1]) + y1[0] * sigmoidf_(y1[1]) + bOv);
    float cg = tanhf   (z1[2] * sigmoidf_(z1[3]) + y1[2] * sigmoidf_(y1[3]) + bCv);
    c_reg = cg * ig + fg * c_reg;
    float h = og * c_reg;
    out[grow] = h;

    // h store: pack f16 pair (cl even gets cl, cl+1), write-through to LLC
    float hn = __shfl_xor(h, 1);
    if (!(cl & 1)){
      unsigned int pv = (unsigned)f2h_u(h) | ((unsigned)f2h_u(hn) << 16);
      const unsigned short* hw = hhist + (size_t)(s + 1) * 65536 + (size_t)cb * 1024 + n0 + cl;
      asm volatile("global_store_dword %0, %1, off sc0 sc1" :: "v"(hw), "v"(pv) : "memory");
    }
    if (s == 255){
      out[16777216 + cb * 1024 + n0 + cl] = h;
      out[16777216 + 65536 + cb * 1024 + n0 + cl] = c_reg;
      break;   // no barrier after last step
    }

    // ---- Phase E: drain h stores, signal arrival ----
    asm volatile("s_waitcnt vmcnt(0)" ::: "memory");
    __syncthreads();
    if (tid == 0){
      unsigned int v = (unsigned)(s + 1);
      asm volatile("global_store_dword %0, %1, off sc0 sc1" :: "v"(flags + bi), "v"(v) : "memory");
    }
  }
}

// ---------- host launch ----------
extern "C" void kernel_launch(void* const* d_in, const int* in_sizes, int n_in,
                              void* d_out, int out_size, void* d_ws, size_t ws_size,
                              hipStream_t stream){
  (void)in_sizes; (void)n_in; (void)out_size; (void)ws_size;
  char* ws = (char*)d_ws;
  unsigned short* xh    = (unsigned short*)(ws);               // 33,554,432 B
  unsigned short* up    = (unsigned short*)(ws + 33554432);    // 16,777,216 B
  unsigned short* wp    = (unsigned short*)(ws + 50331648);    // 16,777,216 B
  unsigned short* hhist = (unsigned short*)(ws + 67108864);    // 257*131072 = 33,685,504 B
  unsigned int*   flags = (unsigned int*)  (ws + 100794368);   // 1,024 B
  // total: 100,795,392 B (~96.1 MB)

  hipMemsetAsync(hhist, 0, 131072, stream);   // h_{-1} slot = 0
  hipMemsetAsync(flags, 0, 1024, stream);     // barrier flags reset

  cvt_x<<<16384, 256, 0, stream>>>((const float*)d_in[0], xh);
  P8 w8, u8;
  for (int m = 0; m < 8; ++m){
    w8.p[m] = (const float*)d_in[1 + m];
    u8.p[m] = (const float*)d_in[9 + m];
  }
  pack8<<<8192, 256, 0, stream>>>(w8, wp);
  pack8<<<8192, 256, 0, stream>>>(u8, up);

  const float* bF = (const float*)d_in[17];
  const float* bI = (const float*)d_in[18];
  const float* bO = (const float*)d_in[19];
  const float* bC = (const float*)d_in[20];
  float* outp = (float*)d_out;

  void* args[] = { (void*)&xh, (void*)&up, (void*)&wp,
                   (void*)&bF, (void*)&bI, (void*)&bO, (void*)&bC,
                   (void*)&hhist, (void*)&flags, (void*)&outp };
  hipError_t e = hipLaunchCooperativeKernel((const void*)lstm_rec, dim3(256), dim3(256),
                                            args, 0u, stream);
  if (e != hipSuccess){
    lstm_rec<<<256, 256, 0, stream>>>(xh, up, wp, bF, bI, bO, bC, hhist, flags, outp);
  }
}